// Round 1
// baseline (392.488 us; speedup 1.0000x reference)
//
#include <hip/hip_runtime.h>

// GraphSAGE 2-layer inference, fp32.
// N=40000 nodes, E=640000 edges, C=128 channels, OUT=121.
// Strategy: build CSR once (histogram + 3-phase scan + scatter), then
// [aggregate -> fused dual-GEMM] per layer. All fp32 (no MFMA: CDNA4 has no
// fp32-input MFMA; bf16 MFMA is a candidate for later rounds).

#define NCH 128
#define BM 64
#define BN 128
#define KB 32

// ---------------- CSR build ----------------

__global__ void k_zero(int* __restrict__ p, int n) {
  int i = blockIdx.x * blockDim.x + threadIdx.x;
  if (i < n) p[i] = 0;
}

__global__ void k_hist(const int* __restrict__ dst, int* __restrict__ cnt, int E) {
  int e = blockIdx.x * blockDim.x + threadIdx.x;
  if (e < E) atomicAdd(&cnt[dst[e]], 1);
}

// phase 1: per-block (1024 elems) exclusive scan, block totals to btot
__global__ void k_scan1(const int* __restrict__ cnt, int* __restrict__ off,
                        int* __restrict__ btot, int n) {
  int i = blockIdx.x * 1024 + (int)threadIdx.x;
  int v = (i < n) ? cnt[i] : 0;
  int lane = threadIdx.x & 63;
  int wv = threadIdx.x >> 6;
  int x = v;
#pragma unroll
  for (int d = 1; d < 64; d <<= 1) {
    int t = __shfl_up(x, d);
    if (lane >= d) x += t;
  }
  __shared__ int wt[16];
  if (lane == 63) wt[wv] = x;
  __syncthreads();
  if (threadIdx.x < 16) {
    int t = wt[threadIdx.x];
#pragma unroll
    for (int d = 1; d < 16; d <<= 1) {
      int u = __shfl_up(t, d);
      if (lane >= d) t += u;
    }
    wt[threadIdx.x] = t;
  }
  __syncthreads();
  int base = (wv > 0) ? wt[wv - 1] : 0;
  int incl = x + base;
  if (i < n) off[i] = incl - v;  // block-local exclusive
  if (threadIdx.x == 1023) btot[blockIdx.x] = incl;
}

// phase 2: one wave scans the (<=64) block totals; also writes off[n]=E
__global__ void k_scan2(const int* __restrict__ btot, int* __restrict__ bpre,
                        int* __restrict__ off, int nblocks, int n, int E) {
  int tid = threadIdx.x;  // 64 threads
  int v = (tid < nblocks) ? btot[tid] : 0;
  int x = v;
#pragma unroll
  for (int d = 1; d < 64; d <<= 1) {
    int t = __shfl_up(x, d);
    if (tid >= d) x += t;
  }
  if (tid < nblocks) bpre[tid] = x - v;  // exclusive
  if (tid == 0) off[n] = E;
}

// phase 3: add block base, also init scatter cursor
__global__ void k_scan3(int* __restrict__ off, int* __restrict__ cursor,
                        const int* __restrict__ bpre, int n) {
  int i = blockIdx.x * blockDim.x + threadIdx.x;
  if (i < n) {
    int o = off[i] + bpre[i >> 10];
    off[i] = o;
    cursor[i] = o;
  }
}

__global__ void k_scatter(const int* __restrict__ src, const int* __restrict__ dst,
                          int* __restrict__ cursor, int* __restrict__ esrc, int E) {
  int e = blockIdx.x * blockDim.x + threadIdx.x;
  if (e < E) {
    int d = dst[e];
    int pos = atomicAdd(&cursor[d], 1);
    esrc[pos] = src[e];
  }
}

// ---------------- mean aggregation ----------------
// one block (128 threads) per dst node; thread = channel; edge list contiguous
__global__ void k_aggregate(const float* __restrict__ feat, const int* __restrict__ off,
                            const int* __restrict__ esrc, float* __restrict__ agg) {
  int n = blockIdx.x;
  int ch = threadIdx.x;
  int b = off[n], e = off[n + 1];
  float sum = 0.f;
  for (int j = b; j < e; ++j) {
    int s = esrc[j];
    sum += feat[(long)s * NCH + ch];
  }
  int deg = e - b;
  if (deg < 1) deg = 1;
  agg[(long)n * NCH + ch] = sum / (float)deg;
}

// ---------------- fused dual GEMM ----------------
// out[m][no] = relu?( sum_k A[m][k]*Wl[no][k] + B[m][k]*Wr[no][k] + bl[no]+br[no] )
// BM=64 rows x BN=128 cols per block, 256 threads, 8x4 register tile.
// Virtual K'=256 (chunks 0..3 from A/Wl, 4..7 from B/Wr), staged K-transposed
// in LDS so compute reads are ds_read_b128 conflict-free.
__global__ __launch_bounds__(256) void k_gemm(
    const float* __restrict__ A, const float* __restrict__ B,
    const float* __restrict__ Wl, const float* __restrict__ Wr,
    const float* __restrict__ bl, const float* __restrict__ br,
    float* __restrict__ out, int M, int NO, int do_relu) {
  __shared__ __align__(16) float As[KB][BM + 4];   // [k][m]
  __shared__ __align__(16) float Ws[KB][BN + 4];   // [k][n]
  const int tid = threadIdx.x;
  const int tx = tid & 31;   // n-group: n = tx*4 + j
  const int ty = tid >> 5;   // m-group: m = ty*8 + i
  const int m0 = blockIdx.x * BM;

  float acc[8][4];
#pragma unroll
  for (int i = 0; i < 8; ++i)
#pragma unroll
    for (int j = 0; j < 4; ++j) acc[i][j] = 0.f;

  for (int c = 0; c < 8; ++c) {
    const float* __restrict__ S = (c < 4) ? A : B;
    const float* __restrict__ W = (c < 4) ? Wl : Wr;
    const int k0 = (c & 3) * KB;

    // stage A chunk: 64 rows x 32 k -> As[k][m]; 512 float4, 2/thread
#pragma unroll
    for (int t = 0; t < 2; ++t) {
      int idx = tid + t * 256;  // 0..511
      int row = idx >> 3;
      int q = idx & 7;
      int r = m0 + row;
      if (r >= M) r = M - 1;
      const float4 v = *(const float4*)&S[(long)r * NCH + k0 + q * 4];
      As[q * 4 + 0][row] = v.x;
      As[q * 4 + 1][row] = v.y;
      As[q * 4 + 2][row] = v.z;
      As[q * 4 + 3][row] = v.w;
    }
    // stage W chunk: 128 rows x 32 k -> Ws[k][n]; 1024 float4, 4/thread
#pragma unroll
    for (int t = 0; t < 4; ++t) {
      int idx = tid + t * 256;  // 0..1023
      int row = idx >> 3;
      int q = idx & 7;
      int wrow = (row < NO) ? row : (NO - 1);
      const float4 v = *(const float4*)&W[(long)wrow * NCH + k0 + q * 4];
      Ws[q * 4 + 0][row] = v.x;
      Ws[q * 4 + 1][row] = v.y;
      Ws[q * 4 + 2][row] = v.z;
      Ws[q * 4 + 3][row] = v.w;
    }
    __syncthreads();

#pragma unroll 8
    for (int k = 0; k < KB; ++k) {
      float4 a0 = *(const float4*)&As[k][ty * 8 + 0];
      float4 a1 = *(const float4*)&As[k][ty * 8 + 4];
      float4 w = *(const float4*)&Ws[k][tx * 4];
      float av[8] = {a0.x, a0.y, a0.z, a0.w, a1.x, a1.y, a1.z, a1.w};
      float wv[4] = {w.x, w.y, w.z, w.w};
#pragma unroll
      for (int i = 0; i < 8; ++i)
#pragma unroll
        for (int j = 0; j < 4; ++j) acc[i][j] += av[i] * wv[j];
    }
    __syncthreads();
  }

#pragma unroll
  for (int i = 0; i < 8; ++i) {
    int m = m0 + ty * 8 + i;
    if (m >= M) continue;
#pragma unroll
    for (int j = 0; j < 4; ++j) {
      int n = tx * 4 + j;
      if (n < NO) {
        float v = acc[i][j] + bl[n] + br[n];
        if (do_relu) v = fmaxf(v, 0.f);
        out[(long)m * NO + n] = v;
      }
    }
  }
}

// ---------------- launch ----------------

extern "C" void kernel_launch(void* const* d_in, const int* in_sizes, int n_in,
                              void* d_out, int out_size, void* d_ws, size_t ws_size,
                              hipStream_t stream) {
  const float* x = (const float*)d_in[0];
  const int* ei = (const int*)d_in[1];
  const float* W1l = (const float*)d_in[2];
  const float* b1l = (const float*)d_in[3];
  const float* W1r = (const float*)d_in[4];
  const float* b1r = (const float*)d_in[5];
  const float* W2l = (const float*)d_in[6];
  const float* b2l = (const float*)d_in[7];
  const float* W2r = (const float*)d_in[8];
  const float* b2r = (const float*)d_in[9];
  float* out = (float*)d_out;

  const int N = in_sizes[0] / NCH;  // 40000
  const int E = in_sizes[1] / 2;    // 640000
  const int NOUT = out_size / N;    // 121

  const int* src = ei;
  const int* dst = ei + E;

  char* w = (char*)d_ws;
  auto alloc = [&](size_t bytes) {
    char* p = w;
    w += (bytes + 255) & ~(size_t)255;
    return p;
  };
  float* agg = (float*)alloc((size_t)N * NCH * 4);
  float* h = (float*)alloc((size_t)N * NCH * 4);
  int* esrc = (int*)alloc((size_t)E * 4);
  int* off = (int*)alloc((size_t)(N + 1) * 4);
  int* cursor = (int*)alloc((size_t)N * 4);
  int* cnt = (int*)alloc((size_t)N * 4);
  int* btot = (int*)alloc(64 * 4);
  int* bpre = (int*)alloc(64 * 4);

  const int nb1024 = (N + 1023) / 1024;  // 40

  k_zero<<<(N + 255) / 256, 256, 0, stream>>>(cnt, N);
  k_hist<<<(E + 255) / 256, 256, 0, stream>>>(dst, cnt, E);
  k_scan1<<<nb1024, 1024, 0, stream>>>(cnt, off, btot, N);
  k_scan2<<<1, 64, 0, stream>>>(btot, bpre, off, nb1024, N, E);
  k_scan3<<<(N + 255) / 256, 256, 0, stream>>>(off, cursor, bpre, N);
  k_scatter<<<(E + 255) / 256, 256, 0, stream>>>(src, dst, cursor, esrc, E);

  // layer 1
  k_aggregate<<<N, NCH, 0, stream>>>(x, off, esrc, agg);
  k_gemm<<<(N + BM - 1) / BM, 256, 0, stream>>>(agg, x, W1l, W1r, b1l, b1r, h, N, NCH, 1);
  // layer 2
  k_aggregate<<<N, NCH, 0, stream>>>(h, off, esrc, agg);
  k_gemm<<<(N + BM - 1) / BM, 256, 0, stream>>>(agg, h, W2l, W2r, b2l, b2r, out, N, NOUT, 0);
}

// Round 2
// 340.162 us; speedup vs baseline: 1.1538x; 1.1538x over previous
//
#include <hip/hip_runtime.h>

// GraphSAGE 2-layer inference, fp32.
// N=40000 nodes, E=640000 edges, C=128 channels, OUT=121.
// CSR build (histogram + 3-phase scan + scatter), then
// [aggregate -> fused dual-GEMM] per layer.
// R2: aggregate rewritten wave-per-node with float4 gathers + 4x unroll
// (R1 profile: k_aggregate 73us, VALUBusy 8%, hbm 28% -> latency-bound,
//  1 dword load in flight per lane; now 4x float4 in flight per lane).

#define NCH 128
#define BM 64
#define BN 128
#define KB 32

// ---------------- CSR build ----------------

__global__ void k_zero(int* __restrict__ p, int n) {
  int i = blockIdx.x * blockDim.x + threadIdx.x;
  if (i < n) p[i] = 0;
}

__global__ void k_hist(const int* __restrict__ dst, int* __restrict__ cnt, int E) {
  int e = blockIdx.x * blockDim.x + threadIdx.x;
  if (e < E) atomicAdd(&cnt[dst[e]], 1);
}

// phase 1: per-block (1024 elems) exclusive scan, block totals to btot
__global__ void k_scan1(const int* __restrict__ cnt, int* __restrict__ off,
                        int* __restrict__ btot, int n) {
  int i = blockIdx.x * 1024 + (int)threadIdx.x;
  int v = (i < n) ? cnt[i] : 0;
  int lane = threadIdx.x & 63;
  int wv = threadIdx.x >> 6;
  int x = v;
#pragma unroll
  for (int d = 1; d < 64; d <<= 1) {
    int t = __shfl_up(x, d);
    if (lane >= d) x += t;
  }
  __shared__ int wt[16];
  if (lane == 63) wt[wv] = x;
  __syncthreads();
  if (threadIdx.x < 16) {
    int t = wt[threadIdx.x];
#pragma unroll
    for (int d = 1; d < 16; d <<= 1) {
      int u = __shfl_up(t, d);
      if (lane >= d) t += u;
    }
    wt[threadIdx.x] = t;
  }
  __syncthreads();
  int base = (wv > 0) ? wt[wv - 1] : 0;
  int incl = x + base;
  if (i < n) off[i] = incl - v;  // block-local exclusive
  if (threadIdx.x == 1023) btot[blockIdx.x] = incl;
}

// phase 2: one wave scans the (<=64) block totals; also writes off[n]=E
__global__ void k_scan2(const int* __restrict__ btot, int* __restrict__ bpre,
                        int* __restrict__ off, int nblocks, int n, int E) {
  int tid = threadIdx.x;  // 64 threads
  int v = (tid < nblocks) ? btot[tid] : 0;
  int x = v;
#pragma unroll
  for (int d = 1; d < 64; d <<= 1) {
    int t = __shfl_up(x, d);
    if (tid >= d) x += t;
  }
  if (tid < nblocks) bpre[tid] = x - v;  // exclusive
  if (tid == 0) off[n] = E;
}

// phase 3: add block base, also init scatter cursor
__global__ void k_scan3(int* __restrict__ off, int* __restrict__ cursor,
                        const int* __restrict__ bpre, int n) {
  int i = blockIdx.x * blockDim.x + threadIdx.x;
  if (i < n) {
    int o = off[i] + bpre[i >> 10];
    off[i] = o;
    cursor[i] = o;
  }
}

__global__ void k_scatter(const int* __restrict__ src, const int* __restrict__ dst,
                          int* __restrict__ cursor, int* __restrict__ esrc, int E) {
  int e = blockIdx.x * blockDim.x + threadIdx.x;
  if (e < E) {
    int d = dst[e];
    int pos = atomicAdd(&cursor[d], 1);
    esrc[pos] = src[e];
  }
}

// ---------------- mean aggregation ----------------
// R2: one WAVE per node. 32 lanes x float4 = 512B row; halves (lane>>5)
// process interleaved edges; 4x unroll -> 4 outstanding 16B loads/lane.
__global__ __launch_bounds__(256) void k_aggregate(
    const float* __restrict__ feat, const int* __restrict__ off,
    const int* __restrict__ esrc, float* __restrict__ agg, int N) {
  const int node = blockIdx.x * 4 + (threadIdx.x >> 6);
  if (node >= N) return;
  const int lane = threadIdx.x & 63;
  const int half = lane >> 5;       // 0 or 1
  const int col = (lane & 31) * 4;  // float4 column within the 128-ch row

  const int b = off[node];
  const int e = off[node + 1];

  float4 s0 = {0.f, 0.f, 0.f, 0.f};
  float4 s1 = {0.f, 0.f, 0.f, 0.f};
  float4 s2 = {0.f, 0.f, 0.f, 0.f};
  float4 s3 = {0.f, 0.f, 0.f, 0.f};

  int j = b + half;
  // main loop: each half consumes edges j, j+2, j+4, j+6 -> 8 edges/wave/iter
  for (; j + 6 < e; j += 8) {
    const int i0 = esrc[j];
    const int i1 = esrc[j + 2];
    const int i2 = esrc[j + 4];
    const int i3 = esrc[j + 6];
    const float4 v0 = *(const float4*)&feat[(long)i0 * NCH + col];
    const float4 v1 = *(const float4*)&feat[(long)i1 * NCH + col];
    const float4 v2 = *(const float4*)&feat[(long)i2 * NCH + col];
    const float4 v3 = *(const float4*)&feat[(long)i3 * NCH + col];
    s0.x += v0.x; s0.y += v0.y; s0.z += v0.z; s0.w += v0.w;
    s1.x += v1.x; s1.y += v1.y; s1.z += v1.z; s1.w += v1.w;
    s2.x += v2.x; s2.y += v2.y; s2.z += v2.z; s2.w += v2.w;
    s3.x += v3.x; s3.y += v3.y; s3.z += v3.z; s3.w += v3.w;
  }
  for (; j < e; j += 2) {
    const int s = esrc[j];
    const float4 v = *(const float4*)&feat[(long)s * NCH + col];
    s0.x += v.x; s0.y += v.y; s0.z += v.z; s0.w += v.w;
  }

  float sx = s0.x + s1.x + s2.x + s3.x;
  float sy = s0.y + s1.y + s2.y + s3.y;
  float sz = s0.z + s1.z + s2.z + s3.z;
  float sw = s0.w + s1.w + s2.w + s3.w;
  // combine the two halves (lane ^ 32 holds the same column)
  sx += __shfl_xor(sx, 32);
  sy += __shfl_xor(sy, 32);
  sz += __shfl_xor(sz, 32);
  sw += __shfl_xor(sw, 32);

  if (half == 0) {
    int deg = e - b;
    if (deg < 1) deg = 1;
    const float inv = 1.f / (float)deg;
    float4 r;
    r.x = sx * inv; r.y = sy * inv; r.z = sz * inv; r.w = sw * inv;
    *(float4*)&agg[(long)node * NCH + col] = r;
  }
}

// ---------------- fused dual GEMM ----------------
// out[m][no] = relu?( sum_k A[m][k]*Wl[no][k] + B[m][k]*Wr[no][k] + bl[no]+br[no] )
__global__ __launch_bounds__(256) void k_gemm(
    const float* __restrict__ A, const float* __restrict__ B,
    const float* __restrict__ Wl, const float* __restrict__ Wr,
    const float* __restrict__ bl, const float* __restrict__ br,
    float* __restrict__ out, int M, int NO, int do_relu) {
  __shared__ __align__(16) float As[KB][BM + 4];   // [k][m]
  __shared__ __align__(16) float Ws[KB][BN + 4];   // [k][n]
  const int tid = threadIdx.x;
  const int tx = tid & 31;   // n-group: n = tx*4 + j
  const int ty = tid >> 5;   // m-group: m = ty*8 + i
  const int m0 = blockIdx.x * BM;

  float acc[8][4];
#pragma unroll
  for (int i = 0; i < 8; ++i)
#pragma unroll
    for (int j = 0; j < 4; ++j) acc[i][j] = 0.f;

  for (int c = 0; c < 8; ++c) {
    const float* __restrict__ S = (c < 4) ? A : B;
    const float* __restrict__ W = (c < 4) ? Wl : Wr;
    const int k0 = (c & 3) * KB;

    // stage A chunk: 64 rows x 32 k -> As[k][m]; 512 float4, 2/thread
#pragma unroll
    for (int t = 0; t < 2; ++t) {
      int idx = tid + t * 256;  // 0..511
      int row = idx >> 3;
      int q = idx & 7;
      int r = m0 + row;
      if (r >= M) r = M - 1;
      const float4 v = *(const float4*)&S[(long)r * NCH + k0 + q * 4];
      As[q * 4 + 0][row] = v.x;
      As[q * 4 + 1][row] = v.y;
      As[q * 4 + 2][row] = v.z;
      As[q * 4 + 3][row] = v.w;
    }
    // stage W chunk: 128 rows x 32 k -> Ws[k][n]; 1024 float4, 4/thread
#pragma unroll
    for (int t = 0; t < 4; ++t) {
      int idx = tid + t * 256;  // 0..1023
      int row = idx >> 3;
      int q = idx & 7;
      int wrow = (row < NO) ? row : (NO - 1);
      const float4 v = *(const float4*)&W[(long)wrow * NCH + k0 + q * 4];
      Ws[q * 4 + 0][row] = v.x;
      Ws[q * 4 + 1][row] = v.y;
      Ws[q * 4 + 2][row] = v.z;
      Ws[q * 4 + 3][row] = v.w;
    }
    __syncthreads();

#pragma unroll 8
    for (int k = 0; k < KB; ++k) {
      float4 a0 = *(const float4*)&As[k][ty * 8 + 0];
      float4 a1 = *(const float4*)&As[k][ty * 8 + 4];
      float4 w = *(const float4*)&Ws[k][tx * 4];
      float av[8] = {a0.x, a0.y, a0.z, a0.w, a1.x, a1.y, a1.z, a1.w};
      float wv[4] = {w.x, w.y, w.z, w.w};
#pragma unroll
      for (int i = 0; i < 8; ++i)
#pragma unroll
        for (int j = 0; j < 4; ++j) acc[i][j] += av[i] * wv[j];
    }
    __syncthreads();
  }

#pragma unroll
  for (int i = 0; i < 8; ++i) {
    int m = m0 + ty * 8 + i;
    if (m >= M) continue;
#pragma unroll
    for (int j = 0; j < 4; ++j) {
      int n = tx * 4 + j;
      if (n < NO) {
        float v = acc[i][j] + bl[n] + br[n];
        if (do_relu) v = fmaxf(v, 0.f);
        out[(long)m * NO + n] = v;
      }
    }
  }
}

// ---------------- launch ----------------

extern "C" void kernel_launch(void* const* d_in, const int* in_sizes, int n_in,
                              void* d_out, int out_size, void* d_ws, size_t ws_size,
                              hipStream_t stream) {
  const float* x = (const float*)d_in[0];
  const int* ei = (const int*)d_in[1];
  const float* W1l = (const float*)d_in[2];
  const float* b1l = (const float*)d_in[3];
  const float* W1r = (const float*)d_in[4];
  const float* b1r = (const float*)d_in[5];
  const float* W2l = (const float*)d_in[6];
  const float* b2l = (const float*)d_in[7];
  const float* W2r = (const float*)d_in[8];
  const float* b2r = (const float*)d_in[9];
  float* out = (float*)d_out;

  const int N = in_sizes[0] / NCH;  // 40000
  const int E = in_sizes[1] / 2;    // 640000
  const int NOUT = out_size / N;    // 121

  const int* src = ei;
  const int* dst = ei + E;

  char* w = (char*)d_ws;
  auto alloc = [&](size_t bytes) {
    char* p = w;
    w += (bytes + 255) & ~(size_t)255;
    return p;
  };
  float* agg = (float*)alloc((size_t)N * NCH * 4);
  float* h = (float*)alloc((size_t)N * NCH * 4);
  int* esrc = (int*)alloc((size_t)E * 4);
  int* off = (int*)alloc((size_t)(N + 1) * 4);
  int* cursor = (int*)alloc((size_t)N * 4);
  int* cnt = (int*)alloc((size_t)N * 4);
  int* btot = (int*)alloc(64 * 4);
  int* bpre = (int*)alloc(64 * 4);

  const int nb1024 = (N + 1023) / 1024;  // 40

  k_zero<<<(N + 255) / 256, 256, 0, stream>>>(cnt, N);
  k_hist<<<(E + 255) / 256, 256, 0, stream>>>(dst, cnt, E);
  k_scan1<<<nb1024, 1024, 0, stream>>>(cnt, off, btot, N);
  k_scan2<<<1, 64, 0, stream>>>(btot, bpre, off, nb1024, N, E);
  k_scan3<<<(N + 255) / 256, 256, 0, stream>>>(off, cursor, bpre, N);
  k_scatter<<<(E + 255) / 256, 256, 0, stream>>>(src, dst, cursor, esrc, E);

  // layer 1
  k_aggregate<<<(N + 3) / 4, 256, 0, stream>>>(x, off, esrc, agg, N);
  k_gemm<<<(N + BM - 1) / BM, 256, 0, stream>>>(agg, x, W1l, W1r, b1l, b1r, h, N, NCH, 1);
  // layer 2
  k_aggregate<<<(N + 3) / 4, 256, 0, stream>>>(h, off, esrc, agg, N);
  k_gemm<<<(N + BM - 1) / BM, 256, 0, stream>>>(agg, h, W2l, W2r, b2l, b2r, out, N, NOUT, 0);
}

// Round 3
// 251.242 us; speedup vs baseline: 1.5622x; 1.3539x over previous
//
#include <hip/hip_runtime.h>

// GraphSAGE 2-layer inference. N=40000, E=640000, C=128, OUT=121.
// R3: bf16 MFMA GEMMs (LDS-free, weights prepacked in B-frag order),
// bf16 gathers in aggregation (fp32 accumulate). CSR build unchanged.

#define NCH 128

typedef __bf16 bf16x8 __attribute__((ext_vector_type(8)));
typedef float f32x4 __attribute__((ext_vector_type(4)));

static __device__ __forceinline__ unsigned short f2b(float f) {
  return __builtin_bit_cast(unsigned short, static_cast<__bf16>(f));
}
static __device__ __forceinline__ float b2f(unsigned short u) {
  union { unsigned int i; float f; } v;
  v.i = ((unsigned int)u) << 16;
  return v.f;
}

// ---------------- CSR build ----------------

__global__ void k_zero(int* __restrict__ p, int n) {
  int i = blockIdx.x * blockDim.x + threadIdx.x;
  if (i < n) p[i] = 0;
}

__global__ void k_hist(const int* __restrict__ dst, int* __restrict__ cnt, int E) {
  int e = blockIdx.x * blockDim.x + threadIdx.x;
  if (e < E) atomicAdd(&cnt[dst[e]], 1);
}

__global__ void k_scan1(const int* __restrict__ cnt, int* __restrict__ off,
                        int* __restrict__ btot, int n) {
  int i = blockIdx.x * 1024 + (int)threadIdx.x;
  int v = (i < n) ? cnt[i] : 0;
  int lane = threadIdx.x & 63;
  int wv = threadIdx.x >> 6;
  int x = v;
#pragma unroll
  for (int d = 1; d < 64; d <<= 1) {
    int t = __shfl_up(x, d);
    if (lane >= d) x += t;
  }
  __shared__ int wt[16];
  if (lane == 63) wt[wv] = x;
  __syncthreads();
  if (threadIdx.x < 16) {
    int t = wt[threadIdx.x];
#pragma unroll
    for (int d = 1; d < 16; d <<= 1) {
      int u = __shfl_up(t, d);
      if (lane >= d) t += u;
    }
    wt[threadIdx.x] = t;
  }
  __syncthreads();
  int base = (wv > 0) ? wt[wv - 1] : 0;
  int incl = x + base;
  if (i < n) off[i] = incl - v;
  if (threadIdx.x == 1023) btot[blockIdx.x] = incl;
}

__global__ void k_scan2(const int* __restrict__ btot, int* __restrict__ bpre,
                        int* __restrict__ off, int nblocks, int n, int E) {
  int tid = threadIdx.x;  // 64
  int v = (tid < nblocks) ? btot[tid] : 0;
  int x = v;
#pragma unroll
  for (int d = 1; d < 64; d <<= 1) {
    int t = __shfl_up(x, d);
    if (tid >= d) x += t;
  }
  if (tid < nblocks) bpre[tid] = x - v;
  if (tid == 0) off[n] = E;
}

__global__ void k_scan3(int* __restrict__ off, int* __restrict__ cursor,
                        const int* __restrict__ bpre, int n) {
  int i = blockIdx.x * blockDim.x + threadIdx.x;
  if (i < n) {
    int o = off[i] + bpre[i >> 10];
    off[i] = o;
    cursor[i] = o;
  }
}

__global__ void k_scatter(const int* __restrict__ src, const int* __restrict__ dst,
                          int* __restrict__ cursor, int* __restrict__ esrc, int E) {
  int e = blockIdx.x * blockDim.x + threadIdx.x;
  if (e < E) {
    int d = dst[e];
    int pos = atomicAdd(&cursor[d], 1);
    esrc[pos] = src[e];
  }
}

// ---------------- fp32 -> bf16 convert ----------------
__global__ void k_tobf16(const float* __restrict__ in, unsigned short* __restrict__ out,
                         int n4) {
  int i = blockIdx.x * blockDim.x + threadIdx.x;
  if (i < n4) {
    float4 v = ((const float4*)in)[i];
    ushort4 r;
    r.x = f2b(v.x); r.y = f2b(v.y); r.z = f2b(v.z); r.w = f2b(v.w);
    ((ushort4*)out)[i] = r;
  }
}

// ---------------- weight prepack into B-fragment order ----------------
// W'[k][n]: k<128 -> Wl[n][k], k>=128 -> Wr[n][k-128]; n>=NO -> 0.
// pack[c][t][lane][j] = W'[c*32 + (lane>>4)*8 + j][t*16 + (lane&15)]
// (B-frag layout for mfma_f32_16x16x32_bf16: n=lane&15, k=(lane>>4)*8+j)
__global__ void k_prepack(const float* __restrict__ Wl, const float* __restrict__ Wr,
                          const float* __restrict__ bl, const float* __restrict__ br,
                          unsigned short* __restrict__ pack, float* __restrict__ bsum,
                          int NO) {
  int tid = blockIdx.x * 256 + threadIdx.x;  // 0..4095
  int c = tid >> 9;
  int t = (tid >> 6) & 7;
  int l = tid & 63;
  int n = t * 16 + (l & 15);
  int kb = c * 32 + ((l >> 4) << 3);
  ushort4 lo, hi;
  unsigned short o[8];
#pragma unroll
  for (int j = 0; j < 8; ++j) {
    int k = kb + j;
    float v = 0.f;
    if (n < NO) v = (k < 128) ? Wl[n * 128 + k] : Wr[n * 128 + (k - 128)];
    o[j] = f2b(v);
  }
  lo.x = o[0]; lo.y = o[1]; lo.z = o[2]; lo.w = o[3];
  hi.x = o[4]; hi.y = o[5]; hi.z = o[6]; hi.w = o[7];
  *(ushort4*)(pack + (long)tid * 8) = lo;
  *(ushort4*)(pack + (long)tid * 8 + 4) = hi;
  if (tid < 128) bsum[tid] = (tid < NO) ? (bl[tid] + br[tid]) : 0.f;
}

// ---------------- mean aggregation (bf16 gather, fp32 accum) ----------------
// one wave per node; 32 lanes x ushort4 (8B) cover the 256B bf16 row;
// halves process alternating edges, 4x unroll -> 4 outstanding loads/lane.
__global__ __launch_bounds__(256) void k_aggregate(
    const unsigned short* __restrict__ feat, const int* __restrict__ off,
    const int* __restrict__ esrc, unsigned short* __restrict__ agg, int N) {
  const int node = blockIdx.x * 4 + (threadIdx.x >> 6);
  if (node >= N) return;
  const int lane = threadIdx.x & 63;
  const int half = lane >> 5;
  const int col = (lane & 31) * 4;

  const int b = off[node];
  const int e = off[node + 1];

  float a0 = 0.f, a1 = 0.f, a2 = 0.f, a3 = 0.f;
  float b0 = 0.f, b1 = 0.f, b2 = 0.f, b3 = 0.f;
  float c0 = 0.f, c1 = 0.f, c2 = 0.f, c3 = 0.f;
  float d0 = 0.f, d1 = 0.f, d2 = 0.f, d3 = 0.f;

  int j = b + half;
  for (; j + 6 < e; j += 8) {
    const int i0 = esrc[j];
    const int i1 = esrc[j + 2];
    const int i2 = esrc[j + 4];
    const int i3 = esrc[j + 6];
    const ushort4 v0 = *(const ushort4*)&feat[(long)i0 * NCH + col];
    const ushort4 v1 = *(const ushort4*)&feat[(long)i1 * NCH + col];
    const ushort4 v2 = *(const ushort4*)&feat[(long)i2 * NCH + col];
    const ushort4 v3 = *(const ushort4*)&feat[(long)i3 * NCH + col];
    a0 += b2f(v0.x); a1 += b2f(v0.y); a2 += b2f(v0.z); a3 += b2f(v0.w);
    b0 += b2f(v1.x); b1 += b2f(v1.y); b2 += b2f(v1.z); b3 += b2f(v1.w);
    c0 += b2f(v2.x); c1 += b2f(v2.y); c2 += b2f(v2.z); c3 += b2f(v2.w);
    d0 += b2f(v3.x); d1 += b2f(v3.y); d2 += b2f(v3.z); d3 += b2f(v3.w);
  }
  for (; j < e; j += 2) {
    const int s = esrc[j];
    const ushort4 v = *(const ushort4*)&feat[(long)s * NCH + col];
    a0 += b2f(v.x); a1 += b2f(v.y); a2 += b2f(v.z); a3 += b2f(v.w);
  }

  float sx = a0 + b0 + c0 + d0;
  float sy = a1 + b1 + c1 + d1;
  float sz = a2 + b2 + c2 + d2;
  float sw = a3 + b3 + c3 + d3;
  sx += __shfl_xor(sx, 32);
  sy += __shfl_xor(sy, 32);
  sz += __shfl_xor(sz, 32);
  sw += __shfl_xor(sw, 32);

  if (half == 0) {
    int deg = e - b;
    if (deg < 1) deg = 1;
    const float inv = 1.f / (float)deg;
    ushort4 r;
    r.x = f2b(sx * inv); r.y = f2b(sy * inv);
    r.z = f2b(sz * inv); r.w = f2b(sw * inv);
    *(ushort4*)&agg[(long)node * NCH + col] = r;
  }
}

// ---------------- MFMA dual-GEMM ----------------
// out[m][n] = relu?( sum_k agg[m][k]Wl[n][k] + self[m][k]Wr[n][k] + bias[n] )
// LDS-free: wave handles 32 rows x 128 cols; K'=256 in 8 chunks of 32;
// A-frags from global bf16 (16B/lane), B-frags from prepacked pack (L1/L2-hot).
__global__ __launch_bounds__(256) void k_gemm(
    const unsigned short* __restrict__ Ag,   // agg   bf16 [M][128]
    const unsigned short* __restrict__ Sf,   // self  bf16 [M][128]
    const unsigned short* __restrict__ pack, // [8][8][64][8] bf16
    const float* __restrict__ bsum,          // [128]
    unsigned short* __restrict__ outb,       // bf16 out (layer1) or null
    float* __restrict__ outf,                // f32 out (layer2) or null
    int M, int NO, int do_relu) {
  const int wave = threadIdx.x >> 6;
  const int lane = threadIdx.x & 63;
  const int R = blockIdx.x * 128 + wave * 32;  // 2 m-tiles: R, R+16
  const int mrow = lane & 15;
  const int koct = (lane >> 4) * 8;

  int r0 = R + mrow;       if (r0 > M - 1) r0 = M - 1;
  int r1 = R + 16 + mrow;  if (r1 > M - 1) r1 = M - 1;

  f32x4 acc[2][8];
#pragma unroll
  for (int mt = 0; mt < 2; ++mt)
#pragma unroll
    for (int t = 0; t < 8; ++t) acc[mt][t] = (f32x4){0.f, 0.f, 0.f, 0.f};

#pragma unroll
  for (int c = 0; c < 8; ++c) {
    const unsigned short* __restrict__ Abase = (c < 4) ? Ag : Sf;
    const int k0 = (c & 3) * 32;
    const bf16x8 a0 = *(const bf16x8*)(Abase + (long)r0 * NCH + k0 + koct);
    const bf16x8 a1 = *(const bf16x8*)(Abase + (long)r1 * NCH + k0 + koct);
    const unsigned short* bp = pack + ((long)(c * 8) * 64 + lane) * 8;
#pragma unroll
    for (int t = 0; t < 8; ++t) {
      const bf16x8 bfrag = *(const bf16x8*)(bp + (long)t * 512);
      acc[0][t] = __builtin_amdgcn_mfma_f32_16x16x32_bf16(a0, bfrag, acc[0][t], 0, 0, 0);
      acc[1][t] = __builtin_amdgcn_mfma_f32_16x16x32_bf16(a1, bfrag, acc[1][t], 0, 0, 0);
    }
  }

  // epilogue: C/D layout col=lane&15, row=(lane>>4)*4+reg
  const int nloc = lane & 15;
  const int rquad = (lane >> 4) * 4;
#pragma unroll
  for (int mt = 0; mt < 2; ++mt) {
#pragma unroll
    for (int t = 0; t < 8; ++t) {
      const int n = t * 16 + nloc;
      const float bias = bsum[n];
#pragma unroll
      for (int r = 0; r < 4; ++r) {
        const int m = R + mt * 16 + rquad + r;
        if (m < M && n < NO) {
          float v = acc[mt][t][r] + bias;
          if (do_relu) v = fmaxf(v, 0.f);
          if (outb) outb[(long)m * NCH + n] = f2b(v);
          else outf[(long)m * NO + n] = v;
        }
      }
    }
  }
}

// ---------------- launch ----------------

extern "C" void kernel_launch(void* const* d_in, const int* in_sizes, int n_in,
                              void* d_out, int out_size, void* d_ws, size_t ws_size,
                              hipStream_t stream) {
  const float* x = (const float*)d_in[0];
  const int* ei = (const int*)d_in[1];
  const float* W1l = (const float*)d_in[2];
  const float* b1l = (const float*)d_in[3];
  const float* W1r = (const float*)d_in[4];
  const float* b1r = (const float*)d_in[5];
  const float* W2l = (const float*)d_in[6];
  const float* b2l = (const float*)d_in[7];
  const float* W2r = (const float*)d_in[8];
  const float* b2r = (const float*)d_in[9];
  float* out = (float*)d_out;

  const int N = in_sizes[0] / NCH;  // 40000
  const int E = in_sizes[1] / 2;    // 640000
  const int NOUT = out_size / N;    // 121

  const int* src = ei;
  const int* dst = ei + E;

  char* w = (char*)d_ws;
  auto alloc = [&](size_t bytes) {
    char* p = w;
    w += (bytes + 255) & ~(size_t)255;
    return p;
  };
  unsigned short* xb = (unsigned short*)alloc((size_t)N * NCH * 2);
  unsigned short* hb = (unsigned short*)alloc((size_t)N * NCH * 2);
  unsigned short* aggb = (unsigned short*)alloc((size_t)N * NCH * 2);
  unsigned short* pack1 = (unsigned short*)alloc(8 * 8 * 64 * 8 * 2);
  unsigned short* pack2 = (unsigned short*)alloc(8 * 8 * 64 * 8 * 2);
  float* bsum1 = (float*)alloc(128 * 4);
  float* bsum2 = (float*)alloc(128 * 4);
  int* esrc = (int*)alloc((size_t)E * 4);
  int* off = (int*)alloc((size_t)(N + 1) * 4);
  int* cursor = (int*)alloc((size_t)N * 4);
  int* cnt = (int*)alloc((size_t)N * 4);
  int* btot = (int*)alloc(64 * 4);
  int* bpre = (int*)alloc(64 * 4);

  const int nb1024 = (N + 1023) / 1024;  // 40

  // CSR build
  k_zero<<<(N + 255) / 256, 256, 0, stream>>>(cnt, N);
  k_hist<<<(E + 255) / 256, 256, 0, stream>>>(dst, cnt, E);
  k_scan1<<<nb1024, 1024, 0, stream>>>(cnt, off, btot, N);
  k_scan2<<<1, 64, 0, stream>>>(btot, bpre, off, nb1024, N, E);
  k_scan3<<<(N + 255) / 256, 256, 0, stream>>>(off, cursor, bpre, N);
  k_scatter<<<(E + 255) / 256, 256, 0, stream>>>(src, dst, cursor, esrc, E);

  // conversions / prepack
  const int n4 = N * NCH / 4;
  k_tobf16<<<(n4 + 255) / 256, 256, 0, stream>>>(x, xb, n4);
  k_prepack<<<16, 256, 0, stream>>>(W1l, W1r, b1l, b1r, pack1, bsum1, NCH);
  k_prepack<<<16, 256, 0, stream>>>(W2l, W2r, b2l, b2r, pack2, bsum2, NOUT);

  const int gblk = (N + 127) / 128;

  // layer 1
  k_aggregate<<<(N + 3) / 4, 256, 0, stream>>>(xb, off, esrc, aggb, N);
  k_gemm<<<gblk, 256, 0, stream>>>(aggb, xb, pack1, bsum1, hb, (float*)nullptr,
                                   N, NCH, 1);
  // layer 2
  k_aggregate<<<(N + 3) / 4, 256, 0, stream>>>(hb, off, esrc, aggb, N);
  k_gemm<<<gblk, 256, 0, stream>>>(aggb, hb, pack2, bsum2, (unsigned short*)nullptr,
                                   out, N, NOUT, 0);
}

// Round 4
// 232.286 us; speedup vs baseline: 1.6897x; 1.0816x over previous
//
#include <hip/hip_runtime.h>

// GraphSAGE 2-layer inference. N=40000, E=640000, C=128, OUT=121.
// R4: (a) aggregation 16-lanes/node x ushort8, 8-deep unroll (4x bytes in
// flight vs R3; R1/R2 showed gathers latency-bound, not BW-bound);
// (b) dispatches 13 -> 9: fused setup kernel (zero + fp32->bf16 + both weight
// prepacks), scan3 folded into scatter/aggregate via bpre add.

#define NCH 128

typedef __bf16 bf16x8 __attribute__((ext_vector_type(8)));
typedef float f32x4 __attribute__((ext_vector_type(4)));
typedef unsigned short ushort8 __attribute__((ext_vector_type(8)));

static __device__ __forceinline__ unsigned short f2b(float f) {
  return __builtin_bit_cast(unsigned short, static_cast<__bf16>(f));
}
static __device__ __forceinline__ float b2f(unsigned short u) {
  union { unsigned int i; float f; } v;
  v.i = ((unsigned int)u) << 16;
  return v.f;
}

// ---------------- fused setup: zero counters, x->bf16, weight prepack ----------------
// pack[c][t][lane][j] = W'[c*32 + (lane>>4)*8 + j][t*16 + (lane&15)]
// (B-frag for mfma_f32_16x16x32_bf16: n=lane&15, k=(lane>>4)*8+j); W' = [Wl;Wr] k-concat.
__global__ __launch_bounds__(256) void k_setup(
    const float* __restrict__ x, unsigned short* __restrict__ xb, int n4,
    int* __restrict__ cnt, int* __restrict__ cur0, int N,
    const float* __restrict__ W1l, const float* __restrict__ W1r,
    const float* __restrict__ b1l, const float* __restrict__ b1r,
    const float* __restrict__ W2l, const float* __restrict__ W2r,
    const float* __restrict__ b2l, const float* __restrict__ b2r,
    unsigned short* __restrict__ pack1, unsigned short* __restrict__ pack2,
    float* __restrict__ bsum1, float* __restrict__ bsum2, int NOUT,
    int nbCvt, int nbZero) {
  int blk = blockIdx.x;
  if (blk < nbCvt) {  // fp32 -> bf16 convert, float4 granularity
    int i = blk * 256 + threadIdx.x;
    if (i < n4) {
      float4 v = ((const float4*)x)[i];
      ushort4 r;
      r.x = f2b(v.x); r.y = f2b(v.y); r.z = f2b(v.z); r.w = f2b(v.w);
      ((ushort4*)xb)[i] = r;
    }
    return;
  }
  blk -= nbCvt;
  if (blk < nbZero) {  // zero hist counters + scatter cursors
    int i = blk * 256 + threadIdx.x;
    if (i < N) { cnt[i] = 0; cur0[i] = 0; }
    return;
  }
  blk -= nbZero;  // prepack: 32 blocks, 16 per layer
  const int layer = blk >> 4;
  const float* Wl = layer ? W2l : W1l;
  const float* Wr = layer ? W2r : W1r;
  const float* bl = layer ? b2l : b1l;
  const float* br = layer ? b2r : b1r;
  unsigned short* pack = layer ? pack2 : pack1;
  float* bsum = layer ? bsum2 : bsum1;
  const int NO = layer ? NOUT : NCH;
  int tid = (blk & 15) * 256 + threadIdx.x;  // 0..4095
  int c = tid >> 9;
  int t = (tid >> 6) & 7;
  int l = tid & 63;
  int n = t * 16 + (l & 15);
  int kb = c * 32 + ((l >> 4) << 3);
  unsigned short o[8];
#pragma unroll
  for (int j = 0; j < 8; ++j) {
    int k = kb + j;
    float v = 0.f;
    if (n < NO) v = (k < 128) ? Wl[n * 128 + k] : Wr[n * 128 + (k - 128)];
    o[j] = f2b(v);
  }
  ushort4 lo, hi;
  lo.x = o[0]; lo.y = o[1]; lo.z = o[2]; lo.w = o[3];
  hi.x = o[4]; hi.y = o[5]; hi.z = o[6]; hi.w = o[7];
  *(ushort4*)(pack + (long)tid * 8) = lo;
  *(ushort4*)(pack + (long)tid * 8 + 4) = hi;
  if (tid < 128) bsum[tid] = (tid < NO) ? (bl[tid] + br[tid]) : 0.f;
}

// ---------------- CSR build ----------------

__global__ void k_hist(const int* __restrict__ dst, int* __restrict__ cnt, int E) {
  int e = blockIdx.x * blockDim.x + threadIdx.x;
  if (e < E) atomicAdd(&cnt[dst[e]], 1);
}

// per-1024-block exclusive scan (block-local) + block totals
__global__ void k_scan1(const int* __restrict__ cnt, int* __restrict__ off,
                        int* __restrict__ btot, int n) {
  int i = blockIdx.x * 1024 + (int)threadIdx.x;
  int v = (i < n) ? cnt[i] : 0;
  int lane = threadIdx.x & 63;
  int wv = threadIdx.x >> 6;
  int x = v;
#pragma unroll
  for (int d = 1; d < 64; d <<= 1) {
    int t = __shfl_up(x, d);
    if (lane >= d) x += t;
  }
  __shared__ int wt[16];
  if (lane == 63) wt[wv] = x;
  __syncthreads();
  if (threadIdx.x < 16) {
    int t = wt[threadIdx.x];
#pragma unroll
    for (int d = 1; d < 16; d <<= 1) {
      int u = __shfl_up(t, d);
      if (lane >= d) t += u;
    }
    wt[threadIdx.x] = t;
  }
  __syncthreads();
  int base = (wv > 0) ? wt[wv - 1] : 0;
  int incl = x + base;
  if (i < n) off[i] = incl - v;
  if (threadIdx.x == 1023) btot[blockIdx.x] = incl;
}

// one wave scans the (<=64) block totals -> bpre (exclusive)
__global__ void k_scan2(const int* __restrict__ btot, int* __restrict__ bpre,
                        int nblocks) {
  int tid = threadIdx.x;  // 64
  int v = (tid < nblocks) ? btot[tid] : 0;
  int x = v;
#pragma unroll
  for (int d = 1; d < 64; d <<= 1) {
    int t = __shfl_up(x, d);
    if (tid >= d) x += t;
  }
  if (tid < nblocks) bpre[tid] = x - v;
}

// scatter edges into CSR order; global offset computed on the fly
__global__ void k_scatter(const int* __restrict__ src, const int* __restrict__ dst,
                          const int* __restrict__ off, const int* __restrict__ bpre,
                          int* __restrict__ cur0, int* __restrict__ esrc, int E) {
  int e = blockIdx.x * blockDim.x + threadIdx.x;
  if (e < E) {
    int d = dst[e];
    int pos = off[d] + bpre[d >> 10] + atomicAdd(&cur0[d], 1);
    esrc[pos] = src[e];
  }
}

// ---------------- mean aggregation (bf16 gather, fp32 accum) ----------------
// R4: 16 lanes per node, ushort8 (16B) per lane covers the 256B row;
// 8-deep unroll -> 8 x 16B outstanding loads per lane.
__global__ __launch_bounds__(256) void k_aggregate(
    const unsigned short* __restrict__ feat, const int* __restrict__ off,
    const int* __restrict__ bpre, const int* __restrict__ esrc,
    unsigned short* __restrict__ agg, int N, int E) {
  const int g = (blockIdx.x * 256 + (int)threadIdx.x) >> 4;  // node
  if (g >= N) return;
  const int col = (threadIdx.x & 15) * 8;

  const int b = off[g] + bpre[g >> 10];
  const int e = (g + 1 < N) ? (off[g + 1] + bpre[(g + 1) >> 10]) : E;

  float acc[8];
#pragma unroll
  for (int k = 0; k < 8; ++k) acc[k] = 0.f;

  const unsigned short* fcol = feat + col;
  int j = b;
  for (; j + 7 < e; j += 8) {
    const int i0 = esrc[j + 0], i1 = esrc[j + 1], i2 = esrc[j + 2], i3 = esrc[j + 3];
    const int i4 = esrc[j + 4], i5 = esrc[j + 5], i6 = esrc[j + 6], i7 = esrc[j + 7];
    const ushort8 v0 = *(const ushort8*)(fcol + (long)i0 * NCH);
    const ushort8 v1 = *(const ushort8*)(fcol + (long)i1 * NCH);
    const ushort8 v2 = *(const ushort8*)(fcol + (long)i2 * NCH);
    const ushort8 v3 = *(const ushort8*)(fcol + (long)i3 * NCH);
    const ushort8 v4 = *(const ushort8*)(fcol + (long)i4 * NCH);
    const ushort8 v5 = *(const ushort8*)(fcol + (long)i5 * NCH);
    const ushort8 v6 = *(const ushort8*)(fcol + (long)i6 * NCH);
    const ushort8 v7 = *(const ushort8*)(fcol + (long)i7 * NCH);
#pragma unroll
    for (int k = 0; k < 8; ++k) {
      acc[k] += b2f(v0[k]); acc[k] += b2f(v1[k]);
      acc[k] += b2f(v2[k]); acc[k] += b2f(v3[k]);
      acc[k] += b2f(v4[k]); acc[k] += b2f(v5[k]);
      acc[k] += b2f(v6[k]); acc[k] += b2f(v7[k]);
    }
  }
  if (j + 3 < e) {
    const int i0 = esrc[j + 0], i1 = esrc[j + 1], i2 = esrc[j + 2], i3 = esrc[j + 3];
    const ushort8 v0 = *(const ushort8*)(fcol + (long)i0 * NCH);
    const ushort8 v1 = *(const ushort8*)(fcol + (long)i1 * NCH);
    const ushort8 v2 = *(const ushort8*)(fcol + (long)i2 * NCH);
    const ushort8 v3 = *(const ushort8*)(fcol + (long)i3 * NCH);
#pragma unroll
    for (int k = 0; k < 8; ++k) {
      acc[k] += b2f(v0[k]); acc[k] += b2f(v1[k]);
      acc[k] += b2f(v2[k]); acc[k] += b2f(v3[k]);
    }
    j += 4;
  }
  for (; j < e; ++j) {
    const ushort8 v = *(const ushort8*)(fcol + (long)esrc[j] * NCH);
#pragma unroll
    for (int k = 0; k < 8; ++k) acc[k] += b2f(v[k]);
  }

  int deg = e - b;
  if (deg < 1) deg = 1;
  const float inv = 1.f / (float)deg;
  ushort8 r;
#pragma unroll
  for (int k = 0; k < 8; ++k) r[k] = f2b(acc[k] * inv);
  *(ushort8*)(agg + (long)g * NCH + col) = r;
}

// ---------------- MFMA dual-GEMM ----------------
// out[m][n] = relu?( sum_k agg[m][k]Wl[n][k] + self[m][k]Wr[n][k] + bias[n] )
// LDS-free: wave = 32 rows x 128 cols; K'=256 in 8 chunks; A-frags from
// global bf16 (16B/lane), B-frags from prepacked pack (L2-hot, 64KB).
__global__ __launch_bounds__(256) void k_gemm(
    const unsigned short* __restrict__ Ag,   // agg  bf16 [M][128]
    const unsigned short* __restrict__ Sf,   // self bf16 [M][128]
    const unsigned short* __restrict__ pack, // [8][8][64][8] bf16
    const float* __restrict__ bsum,          // [128]
    unsigned short* __restrict__ outb,       // bf16 out (layer1) or null
    float* __restrict__ outf,                // f32 out (layer2) or null
    int M, int NO, int do_relu) {
  const int wave = threadIdx.x >> 6;
  const int lane = threadIdx.x & 63;
  const int R = blockIdx.x * 128 + wave * 32;  // 2 m-tiles: R, R+16
  const int mrow = lane & 15;
  const int koct = (lane >> 4) * 8;

  int r0 = R + mrow;       if (r0 > M - 1) r0 = M - 1;
  int r1 = R + 16 + mrow;  if (r1 > M - 1) r1 = M - 1;

  f32x4 acc[2][8];
#pragma unroll
  for (int mt = 0; mt < 2; ++mt)
#pragma unroll
    for (int t = 0; t < 8; ++t) acc[mt][t] = (f32x4){0.f, 0.f, 0.f, 0.f};

#pragma unroll
  for (int c = 0; c < 8; ++c) {
    const unsigned short* __restrict__ Abase = (c < 4) ? Ag : Sf;
    const int k0 = (c & 3) * 32;
    const bf16x8 a0 = *(const bf16x8*)(Abase + (long)r0 * NCH + k0 + koct);
    const bf16x8 a1 = *(const bf16x8*)(Abase + (long)r1 * NCH + k0 + koct);
    const unsigned short* bp = pack + ((long)(c * 8) * 64 + lane) * 8;
#pragma unroll
    for (int t = 0; t < 8; ++t) {
      const bf16x8 bfrag = *(const bf16x8*)(bp + (long)t * 512);
      acc[0][t] = __builtin_amdgcn_mfma_f32_16x16x32_bf16(a0, bfrag, acc[0][t], 0, 0, 0);
      acc[1][t] = __builtin_amdgcn_mfma_f32_16x16x32_bf16(a1, bfrag, acc[1][t], 0, 0, 0);
    }
  }

  // epilogue: C/D layout col=lane&15, row=(lane>>4)*4+reg
  const int nloc = lane & 15;
  const int rquad = (lane >> 4) * 4;
#pragma unroll
  for (int mt = 0; mt < 2; ++mt) {
#pragma unroll
    for (int t = 0; t < 8; ++t) {
      const int n = t * 16 + nloc;
      const float bias = bsum[n];
#pragma unroll
      for (int r = 0; r < 4; ++r) {
        const int m = R + mt * 16 + rquad + r;
        if (m < M && n < NO) {
          float v = acc[mt][t][r] + bias;
          if (do_relu) v = fmaxf(v, 0.f);
          if (outb) outb[(long)m * NCH + n] = f2b(v);
          else outf[(long)m * NO + n] = v;
        }
      }
    }
  }
}

// ---------------- launch ----------------

extern "C" void kernel_launch(void* const* d_in, const int* in_sizes, int n_in,
                              void* d_out, int out_size, void* d_ws, size_t ws_size,
                              hipStream_t stream) {
  const float* x = (const float*)d_in[0];
  const int* ei = (const int*)d_in[1];
  const float* W1l = (const float*)d_in[2];
  const float* b1l = (const float*)d_in[3];
  const float* W1r = (const float*)d_in[4];
  const float* b1r = (const float*)d_in[5];
  const float* W2l = (const float*)d_in[6];
  const float* b2l = (const float*)d_in[7];
  const float* W2r = (const float*)d_in[8];
  const float* b2r = (const float*)d_in[9];
  float* out = (float*)d_out;

  const int N = in_sizes[0] / NCH;  // 40000
  const int E = in_sizes[1] / 2;    // 640000
  const int NOUT = out_size / N;    // 121

  const int* src = ei;
  const int* dst = ei + E;

  char* w = (char*)d_ws;
  auto alloc = [&](size_t bytes) {
    char* p = w;
    w += (bytes + 255) & ~(size_t)255;
    return p;
  };
  unsigned short* xb = (unsigned short*)alloc((size_t)N * NCH * 2);
  unsigned short* hb = (unsigned short*)alloc((size_t)N * NCH * 2);
  unsigned short* aggb = (unsigned short*)alloc((size_t)N * NCH * 2);
  unsigned short* pack1 = (unsigned short*)alloc(8 * 8 * 64 * 8 * 2);
  unsigned short* pack2 = (unsigned short*)alloc(8 * 8 * 64 * 8 * 2);
  float* bsum1 = (float*)alloc(128 * 4);
  float* bsum2 = (float*)alloc(128 * 4);
  int* esrc = (int*)alloc((size_t)E * 4);
  int* off = (int*)alloc((size_t)N * 4);
  int* cur0 = (int*)alloc((size_t)N * 4);
  int* cnt = (int*)alloc((size_t)N * 4);
  int* btot = (int*)alloc(64 * 4);
  int* bpre = (int*)alloc(64 * 4);

  const int nb1024 = (N + 1023) / 1024;  // 40
  const int n4 = N * NCH / 4;
  const int nbCvt = (n4 + 255) / 256;    // 5000
  const int nbZero = (N + 255) / 256;    // 157

  // setup: convert + zero + prepack, one dispatch
  k_setup<<<nbCvt + nbZero + 32, 256, 0, stream>>>(
      x, xb, n4, cnt, cur0, N,
      W1l, W1r, b1l, b1r, W2l, W2r, b2l, b2r,
      pack1, pack2, bsum1, bsum2, NOUT, nbCvt, nbZero);

  // CSR build
  k_hist<<<(E + 255) / 256, 256, 0, stream>>>(dst, cnt, E);
  k_scan1<<<nb1024, 1024, 0, stream>>>(cnt, off, btot, N);
  k_scan2<<<1, 64, 0, stream>>>(btot, bpre, nb1024);
  k_scatter<<<(E + 255) / 256, 256, 0, stream>>>(src, dst, off, bpre, cur0, esrc, E);

  const int gaggr = (N * 16 + 255) / 256;  // 2500
  const int gblk = (N + 127) / 128;        // 313

  // layer 1
  k_aggregate<<<gaggr, 256, 0, stream>>>(xb, off, bpre, esrc, aggb, N, E);
  k_gemm<<<gblk, 256, 0, stream>>>(aggb, xb, pack1, bsum1, hb, (float*)nullptr,
                                   N, NCH, 1);
  // layer 2
  k_aggregate<<<gaggr, 256, 0, stream>>>(hb, off, bpre, esrc, aggb, N, E);
  k_gemm<<<gblk, 256, 0, stream>>>(aggb, hb, pack2, bsum2, (unsigned short*)nullptr,
                                   out, N, NOUT, 0);
}